// Round 12
// baseline (574.230 us; speedup 1.0000x reference)
//
#include <hip/hip_runtime.h>
#include <stdint.h>

#define B_ 512
#define D_ 512
#define C_ 100000
#define CK_ 300000
#define S_ 30.0f
#define COSM_ 0.8775825618903728f
#define SINM_ 0.4794255386042030f
#define TH_ (-0.8775825618903728f)
#define MM_ 0.2397127693021015f
#define EPS_ 1e-12f

#define BM 128
#define BN 96
#define BK 32
/* LDS ushorts: A bufs 3 x 4096 @ [0,12288); B bufs 2 x 3072 @ [12288,18432) */

typedef float f32x4 __attribute__((ext_vector_type(4)));
typedef short s16x8 __attribute__((ext_vector_type(8)));
typedef unsigned long long u64;
typedef unsigned int u32;

#define GLL16(g, l) __builtin_amdgcn_global_load_lds( \
    (const __attribute__((address_space(1))) void*)(g), \
    (__attribute__((address_space(3))) void*)(l), 16, 0, 0)

__device__ __forceinline__ unsigned short f2bf(float f){
  u32 u = __float_as_uint(f);
  u += 0x7FFFu + ((u >> 16) & 1u);
  return (unsigned short)(u >> 16);
}

// ---------------- normalize x rows -> unit bf16 ----------------
__global__ void k_normx(const float* __restrict__ x, unsigned short* __restrict__ xn){
  int row  = blockIdx.x * 4 + (threadIdx.x >> 6);
  int lane = threadIdx.x & 63;
  const float* xr = x + (size_t)row * D_ + lane * 8;
  float4 v0 = *(const float4*)xr;
  float4 v1 = *(const float4*)(xr + 4);
  float s = v0.x*v0.x + v0.y*v0.y + v0.z*v0.z + v0.w*v0.w
          + v1.x*v1.x + v1.y*v1.y + v1.z*v1.z + v1.w*v1.w;
  #pragma unroll
  for (int off = 1; off < 64; off <<= 1) s += __shfl_xor(s, off);
  float inv = 1.f / fmaxf(sqrtf(s), EPS_);
  s16x8 h;
  h[0] = (short)f2bf(v0.x*inv); h[1] = (short)f2bf(v0.y*inv);
  h[2] = (short)f2bf(v0.z*inv); h[3] = (short)f2bf(v0.w*inv);
  h[4] = (short)f2bf(v1.x*inv); h[5] = (short)f2bf(v1.y*inv);
  h[6] = (short)f2bf(v1.z*inv); h[7] = (short)f2bf(v1.w*inv);
  *(s16x8*)(xn + (size_t)row * D_ + lane * 8) = h;
}

// ---------------- zero the per-row reduction buffers ----------------
__global__ void k_init(float* __restrict__ sumexp, u64* __restrict__ packed,
                       float* __restrict__ phi){
  int i = threadIdx.x;
  sumexp[i] = 0.f;
  packed[i] = 0ull;
  phi[i]    = 0.f;
}

// ======= single-pass fused GEMM: 2-step-flight pipeline, frag-linear LDS, 4 blocks/CU =======
__global__ __launch_bounds__(256, 4) void k_gemm(
    const unsigned short* __restrict__ xn, const float* __restrict__ w,
    const int* __restrict__ label,
    float* __restrict__ sumexp_g, u64* __restrict__ packed_g,
    float* __restrict__ phi_g)
{
  __shared__ unsigned short st[18432];   // 36864 B: A 3-buf + B 2-buf
  __shared__ float sqp[192];
  __shared__ int   slab[BM];
  float* mx = (float*)st;                // epilogue overlay [128][33] = 16896 B

  // bijective XCD-chunked mapping (12500 blocks = 8*1562 + 4)
  const int bid = blockIdx.x;
  const int xcd = bid & 7;
  const int i8  = bid >> 3;
  const int seq = (xcd < 4) ? (xcd*1563 + i8) : (6252 + (xcd-4)*1562 + i8);
  const int ct = seq >> 2;                 // column tile (32 classes)
  const int rt = seq & 3;                  // row tile
  const int rowbase = rt * BM;
  const int lcbase  = ct * 32;

  const int tid  = threadIdx.x;
  const int lane = tid & 63;
  const int wid  = tid >> 6;
  const int wm   = wid >> 1, wn = wid & 1; // 2x2 wave grid, wave tile 64x48
  const int lc15 = lane & 15, lhi = lane >> 4;

  if (tid < BM) slab[tid] = label[rowbase + tid];

  // ---- A staging (gl_lds, 2/step): pass p: frag fa = p*4+wid; dest = Abuf + p*2048 + tid*8
  const unsigned short* asrc0 = xn + (size_t)(rowbase + wid*16     + lc15) * D_ + lhi*8;
  const unsigned short* asrc1 = xn + (size_t)(rowbase + (4+wid)*16 + lc15) * D_ + lhi*8;

  // ---- B reg staging (3/step): rr = tid&127; lane_t = rr>>1; hf = rr&1; fb_j = j*2 + (tid>>7)
  const int lane_t = (tid & 127) >> 1, hf = tid & 1;
  const float* bsrc0; const float* bsrc1; const float* bsrc2;
  int bdst0, bdst1, bdst2;   // ushort idx within a B buffer
  {
    #define BSETUP(J, SRC, DST) { \
      int fb = (J)*2 + (tid >> 7); \
      int wn_s = fb / 3, n_s = fb % 3; \
      int wrow = ct*BN + (wn_s*16 + (lane_t & 15))*3 + n_s; \
      SRC = w + (size_t)wrow * D_ + (lane_t >> 4)*8 + hf*4; \
      DST = fb*512 + lane_t*8 + hf*4; }
    BSETUP(0, bsrc0, bdst0)
    BSETUP(1, bsrc1, bdst1)
    BSETUP(2, bsrc2, bdst2)
    #undef BSETUP
  }

  // ---- fragment read offsets (relative to buffer base): base + lane*16B, conflict-free
  int aoff[4], boff[3];
  #pragma unroll
  for (int m = 0; m < 4; ++m) aoff[m] = (wm*4 + m)*512 + lane*8;
  #pragma unroll
  for (int n = 0; n < 3; ++n) boff[n] = (wn*3 + n)*512 + lane*8;

  f32x4 acc[4][3] = {};
  float sq0 = 0.f, sq1 = 0.f, sq2 = 0.f;
  float4 pb0, pb1, pb2;    // B(t+1) regs, loaded one step earlier

#define CVTW(WB, BV, DST, SQ) do{ \
    u32 _c0, _c1; \
    asm("v_cvt_pk_bf16_f32 %0, %1, %2" : "=v"(_c0) : "v"(BV.x), "v"(BV.y)); \
    asm("v_cvt_pk_bf16_f32 %0, %1, %2" : "=v"(_c1) : "v"(BV.z), "v"(BV.w)); \
    *(uint2*)((WB) + (DST)) = make_uint2(_c0, _c1); \
    SQ += BV.x*BV.x + BV.y*BV.y + BV.z*BV.z + BV.w*BV.w; \
  }while(0)

  // ---- prologue: B(0)->regs, A(0)->Abuf0, B(1)->pb, A(1)->Abuf1; write B(0) ----
  {
    float4 c0 = *(const float4*)bsrc0;
    float4 c1 = *(const float4*)bsrc1;
    float4 c2 = *(const float4*)bsrc2;
    asm volatile("" ::: "memory");
    GLL16(asrc0, &st[tid*8]);
    GLL16(asrc1, &st[2048 + tid*8]);
    asm volatile("" ::: "memory");
    pb0 = *(const float4*)(bsrc0 + BK);
    pb1 = *(const float4*)(bsrc1 + BK);
    pb2 = *(const float4*)(bsrc2 + BK);
    asm volatile("" ::: "memory");
    GLL16(asrc0 + BK, &st[4096 + tid*8]);
    GLL16(asrc1 + BK, &st[4096 + 2048 + tid*8]);
    asm volatile("s_waitcnt vmcnt(7)" ::: "memory");   // B(0) regs landed
    unsigned short* wb = &st[12288];
    CVTW(wb, c0, bdst0, sq0);
    CVTW(wb, c1, bdst1, sq1);
    CVTW(wb, c2, bdst2, sq2);
    asm volatile("s_waitcnt lgkmcnt(0)" ::: "memory");
  }

  // step t: issue B(t+2)regs + A(t+2)gl_lds; vmcnt(CW)=A(t) landed; barrier; MFMA(t);
  //         vmcnt(EW)=B(t+1) regs landed; cvt+write B(t+1); lgkm; barrier.
#define STEP(T, ISSUE, DOWRITE, CW, EW) do{                                     \
    float4 nb0 = pb0, nb1 = pb1, nb2 = pb2;                                     \
    if (ISSUE){                                                                 \
      const int k2 = ((T)+2)*BK;                                                \
      nb0 = *(const float4*)(bsrc0 + k2);                                       \
      nb1 = *(const float4*)(bsrc1 + k2);                                       \
      nb2 = *(const float4*)(bsrc2 + k2);                                       \
      asm volatile("" ::: "memory");                                            \
      GLL16(asrc0 + ((T)+2)*BK, &st[(((T)+2)%3)*4096 + tid*8]);                 \
      GLL16(asrc1 + ((T)+2)*BK, &st[(((T)+2)%3)*4096 + 2048 + tid*8]);          \
    }                                                                           \
    asm volatile("s_waitcnt vmcnt(" CW ")" ::: "memory");                       \
    __builtin_amdgcn_s_barrier();                                               \
    asm volatile("" ::: "memory");                                              \
    {                                                                           \
      const unsigned short* ab = &st[((T)%3)*4096];                             \
      const unsigned short* bb = &st[12288 + ((T)&1)*3072];                     \
      s16x8 af[4], bfr[3];                                                      \
      _Pragma("unroll")                                                         \
      for (int m = 0; m < 4; ++m) af[m]  = *(const s16x8*)(ab + aoff[m]);       \
      _Pragma("unroll")                                                         \
      for (int n = 0; n < 3; ++n) bfr[n] = *(const s16x8*)(bb + boff[n]);       \
      __builtin_amdgcn_s_setprio(1);                                            \
      _Pragma("unroll")                                                         \
      for (int m = 0; m < 4; ++m)                                               \
        _Pragma("unroll")                                                       \
        for (int n = 0; n < 3; ++n)                                             \
          acc[m][n] = __builtin_amdgcn_mfma_f32_16x16x32_bf16(af[m], bfr[n], acc[m][n], 0, 0, 0); \
      __builtin_amdgcn_s_setprio(0);                                            \
    }                                                                           \
    if (DOWRITE){                                                               \
      asm volatile("s_waitcnt vmcnt(" EW ")" ::: "memory");                     \
      unsigned short* wb = &st[12288 + (((T)+1)&1)*3072];                       \
      CVTW(wb, pb0, bdst0, sq0);                                                \
      CVTW(wb, pb1, bdst1, sq1);                                                \
      CVTW(wb, pb2, bdst2, sq2);                                                \
      pb0 = nb0; pb1 = nb1; pb2 = nb2;                                          \
      asm volatile("s_waitcnt lgkmcnt(0)" ::: "memory");                        \
    }                                                                           \
    __builtin_amdgcn_s_barrier();                                               \
  }while(0)

  #pragma unroll
  for (int t = 0; t < 14; ++t) STEP(t, 1, 1, "10", "7");
  STEP(14, 0, 1, "5", "2");
  STEP(15, 0, 0, "0", "0");
#undef STEP
#undef CVTW

  // ---- weight-row sumsq fold: ^1 (hf pair), ^32 (k-slice bit), then LDS table
  sq0 += __shfl_xor(sq0, 1); sq0 += __shfl_xor(sq0, 32);
  sq1 += __shfl_xor(sq1, 1); sq1 += __shfl_xor(sq1, 32);
  sq2 += __shfl_xor(sq2, 1); sq2 += __shfl_xor(sq2, 32);
  if ((lane & 33) == 0){
    int c  = (tid >> 1) & 15;
    int hi = tid >> 7;
    int wv = (tid >> 6) & 1;
    sqp[(0 + hi)*32 + c*2 + wv] = sq0;
    sqp[(2 + hi)*32 + c*2 + wv] = sq1;
    sqp[(4 + hi)*32 + c*2 + wv] = sq2;
  }
  __syncthreads();

  float inv_[3];
  #pragma unroll
  for (int n = 0; n < 3; ++n){
    int fb = wn*3 + n;
    float s = sqp[fb*32 + lc15*2] + sqp[fb*32 + lc15*2 + 1];
    inv_[n] = 1.f / fmaxf(sqrtf(s), EPS_);
  }

  // ---- subcenter max in-register; phi at label; write mx (overlay)
  {
    int cls = wn*16 + lc15;
    #pragma unroll
    for (int m = 0; m < 4; ++m){
      #pragma unroll
      for (int r = 0; r < 4; ++r){
        int rl = wm*64 + m*16 + lhi*4 + r;
        float v = fmaxf(fmaxf(acc[m][0][r]*inv_[0], acc[m][1][r]*inv_[1]), acc[m][2][r]*inv_[2]);
        if (slab[rl] - lcbase == cls){
          float cy = v;
          float s2 = fminf(fmaxf(1.f - cy*cy, 0.f), 1.f);
          float sy = sqrtf(s2);
          float ph = cy*COSM_ - sy*SINM_;
          if (!(cy - TH_ > 0.f)) ph = cy - MM_;
          phi_g[rowbase + rl] = ph;        // unique writer
          v = ph;
        }
        mx[rl*33 + cls] = v;
      }
    }
  }
  __syncthreads();

  // ---- per-row LSE + argmax over this block's 32 classes: 2 threads per row
  {
    int row  = tid >> 1;
    int half = tid & 1;
    int grow = rowbase + row;
    float se = 0.f;
    u64 pk = 0ull;
    #pragma unroll
    for (int c = 0; c < 16; ++c){
      int lc = half*16 + c;
      float v = mx[row*33 + lc];
      se += __expf(S_*v - S_);
      u32 u = __float_as_uint(v);
      u = (v >= 0.f) ? (u | 0x80000000u) : ~u;            // sortable float
      u64 p = ((u64)u << 32) | (u32)~(u32)(lcbase + lc);  // ~idx: first-occurrence ties
      pk = (p > pk) ? p : pk;
    }
    se += __shfl_xor(se, 1);
    u32 lo = (u32)pk, hi2 = (u32)(pk >> 32);
    u32 plo = __shfl_xor(lo, 1), phi2 = __shfl_xor(hi2, 1);
    u64 po = ((u64)phi2 << 32) | plo;
    pk = (po > pk) ? po : pk;
    if (half == 0){
      atomicAdd(&sumexp_g[grow], se);
      atomicMax(&packed_g[grow], pk);
    }
  }
}

// ---------------- finalize: loss + prec1 ----------------
__global__ void k_final(const float* __restrict__ sumexp, const u64* __restrict__ packed,
                        const float* __restrict__ phi, const int* __restrict__ label,
                        float* __restrict__ out){
  int i = threadIdx.x;
  float lse  = S_ + logf(sumexp[i]);
  float loss = lse - S_ * phi[i];
  u32 pred = ~(u32)(packed[i] & 0xFFFFFFFFull);
  float corr = (pred == (u32)label[i]) ? 1.f : 0.f;
  float a = loss, b = corr;
  #pragma unroll
  for (int off = 1; off < 64; off <<= 1){ a += __shfl_xor(a, off); b += __shfl_xor(b, off); }
  __shared__ float sa[8], sb[8];
  if ((i & 63) == 0){ sa[i >> 6] = a; sb[i >> 6] = b; }
  __syncthreads();
  if (i == 0){
    float ta = 0.f, tb = 0.f;
    #pragma unroll
    for (int j = 0; j < 8; ++j){ ta += sa[j]; tb += sb[j]; }
    out[0] = ta / 512.f;
    out[1] = tb * (100.f / 512.f);
  }
}

extern "C" void kernel_launch(void* const* d_in, const int* in_sizes, int n_in,
                              void* d_out, int out_size, void* d_ws, size_t ws_size,
                              hipStream_t stream){
  const float* x     = (const float*)d_in[0];
  const int*   label = (const int*)d_in[1];
  const float* w     = (const float*)d_in[2];
  float* out = (float*)d_out;
  char* ws = (char*)d_ws;

  unsigned short* xn = (unsigned short*)ws;            // 524288 B
  float* sumexp = (float*)(ws + 524288);               // 2048 B
  u64*   packed = (u64*)(ws + 524288 + 2048);          // 4096 B
  float* phi    = (float*)(ws + 524288 + 2048 + 4096); // 2048 B

  k_init <<<1,    512, 0, stream>>>(sumexp, packed, phi);
  k_normx<<<B_/4, 256, 0, stream>>>(x, xn);
  k_gemm <<<(CK_/BN)*4, 256, 0, stream>>>(xn, w, label, sumexp, packed, phi);
  k_final<<<1,    512, 0, stream>>>(sumexp, packed, phi, label, out);
}